// Round 1
// 378.808 us; speedup vs baseline: 1.0107x; 1.0107x over previous
//
#include <hip/hip_runtime.h>
#include <hip/hip_bf16.h>
#include <stdint.h>

#define HFR 128
#define HTO 128
#define LDN 136

typedef short short8 __attribute__((ext_vector_type(8)));   // 8 bf16 = 4 VGPRs
typedef float f32x4  __attribute__((ext_vector_type(4)));   // MFMA C/D
typedef unsigned long long u64;

static __device__ __forceinline__ unsigned short f2bf(float x) {
    __hip_bfloat16 h = __float2bfloat16(x);
    return *reinterpret_cast<unsigned short*>(&h);
}
static __device__ __forceinline__ float bflo(unsigned int x) {
    return __uint_as_float(x << 16);           // low bf16 -> f32
}
static __device__ __forceinline__ float bfhi(unsigned int x) {
    return __uint_as_float(x & 0xffff0000u);   // high bf16 -> f32
}

// ---------------------------------------------------------------------------
// zero the degree histogram
// ---------------------------------------------------------------------------
__global__ __launch_bounds__(256) void zero_i32(int* __restrict__ p, int n) {
    int i = blockIdx.x * 256 + threadIdx.x;
    if (i < n) p[i] = 0;
}

// ---------------------------------------------------------------------------
// histogram of destination nodes
// ---------------------------------------------------------------------------
__global__ __launch_bounds__(256)
void count_kernel(const int* __restrict__ rows, int* __restrict__ cnt,
                  int N, int nnz) {
    int e = blockIdx.x * 256 + threadIdx.x;
    if (e >= nnz) return;
    int row = rows[e];
    int r   = row / N;
    int dst = row - r * N;
    atomicAdd(&cnt[dst], 1);
}

// ---------------------------------------------------------------------------
// hierarchical exclusive scan of cnt[0..N), coalesced.
// ---------------------------------------------------------------------------
__global__ __launch_bounds__(256)
void scan_reduce(const int* __restrict__ cnt, int* __restrict__ bsum, int N) {
    __shared__ int s[256];
    int t = threadIdx.x;
    int i = blockIdx.x * 256 + t;
    s[t] = (i < N) ? cnt[i] : 0;
    __syncthreads();
    for (int off = 128; off > 0; off >>= 1) {
        if (t < off) s[t] += s[t + off];
        __syncthreads();
    }
    if (t == 0) bsum[blockIdx.x] = s[0];
}

__global__ __launch_bounds__(1024)
void scan_block(int* __restrict__ bsum, int nb) {
    __shared__ int s[1024];
    int t = threadIdx.x;
    s[t] = (t < nb) ? bsum[t] : 0;
    __syncthreads();
    for (int off = 1; off < 1024; off <<= 1) {
        int o = (t >= off) ? s[t - off] : 0;
        __syncthreads();
        s[t] += o;
        __syncthreads();
    }
    if (t < nb) bsum[t] = (t == 0) ? 0 : s[t - 1];
}

__global__ __launch_bounds__(256)
void scan_final(int* __restrict__ cnt, const int* __restrict__ bsum, int N) {
    __shared__ int s[256];
    int t = threadIdx.x;
    int i = blockIdx.x * 256 + t;
    int v = (i < N) ? cnt[i] : 0;
    s[t] = v;
    __syncthreads();
    for (int off = 1; off < 256; off <<= 1) {
        int o = (t >= off) ? s[t - off] : 0;
        __syncthreads();
        s[t] += o;
        __syncthreads();
    }
    int ex = ((t == 0) ? 0 : s[t - 1]) + bsum[blockIdx.x];
    if (i < N) cnt[i] = ex;     // cnt becomes the segment-start cursor
}

// ---------------------------------------------------------------------------
// pre-convert weights fp32 -> bf16 into MFMA B-fragment layout:
//   Wf[((r*4 + kk)*8 + j)*64 + lane] = short8 of
//      weights[r][j*16 + (lane&15)][kk*32 + (lane>>4)*8 + e], e=0..7
// 256 KB total, L2-resident; each wave's B-frag load is a coalesced 1KB read.
// ---------------------------------------------------------------------------
__global__ __launch_bounds__(256)
void conv_weights(const float* __restrict__ weights, short8* __restrict__ Wf) {
    int id = blockIdx.x * 256 + threadIdx.x;   // 16384 = 8r * 8j * 4kk * 64lane
    int lane = id & 63;
    int kk   = (id >> 6) & 3;
    int j    = (id >> 8) & 7;
    int r    = id >> 11;
    int m = lane & 15, q = lane >> 4;
    const float* src = weights + (((size_t)r * HFR) + j * 16 + m) * HTO + kk * 32 + q * 8;
    short8 sv;
#pragma unroll
    for (int e = 0; e < 8; ++e) sv[e] = f2bf(src[e]);
    Wf[((r * 4 + kk) * 8 + j) * 64 + lane] = sv;
}

// ---------------------------------------------------------------------------
// FUSED kernel: blocks [0, Tblocks) run the MFMA transform, blocks
// [Tblocks, ...) run the counting-sort placement pass.
//
// Round 4 restructure: wt LDS staging removed (B-fragments come pre-swizzled
// from global Wf, L2-hot). LDS = nd only (34816 B) -> 4 blocks/CU = 16
// waves/CU (was 2 blocks / 8 waves). The relation loop is now BARRIER-FREE:
// one __syncthreads after nd staging, then nd is read-only.
// ---------------------------------------------------------------------------
__global__ __launch_bounds__(256, 4)
void fused_tp(const float* __restrict__ nodes,
              const short8* __restrict__ Wf,
              __hip_bfloat16* __restrict__ H,
              const int* __restrict__ rows, const int* __restrict__ cols,
              const float* __restrict__ vals,
              int* __restrict__ cursor, u64* __restrict__ sorted,
              int N, int R, int nnz, int Tblocks) {
    __shared__ unsigned short nd[128 * LDN];

    if ((int)blockIdx.x >= Tblocks) {
        // ---------------- place: counting-sort pass 2 ----------------
        int e = (blockIdx.x - Tblocks) * 256 + threadIdx.x;
        if (e >= nnz) return;
        int row = rows[e];
        int r   = row / N;
        int dst = row - r * N;
        int pos = atomicAdd(&cursor[dst], 1);
        unsigned int lo = (unsigned int)cols[e] | ((unsigned int)r << 17);
        u64 rec = ((u64)__float_as_uint(vals[e]) << 32) | (u64)lo;
        sorted[pos] = rec;
        return;
    }

    // ---------------- transform ----------------
    const int t    = threadIdx.x;
    const int n0   = blockIdx.x * 128;
    const int lane = t & 63;
    const int w    = t >> 6;
    const int m    = lane & 15;
    const int quad = lane >> 4;
    const int q8   = quad * 8;
    const int w32  = w * 32;

    // stage node tile fp32 -> bf16 LDS (once per block)
    const float4* src4 = reinterpret_cast<const float4*>(nodes);
#pragma unroll
    for (int it = 0; it < 8; ++it) {
        int id  = t + 256 * it;
        int row = id >> 4;
        int k8  = id & 15;
        float4 v0 = make_float4(0.f, 0.f, 0.f, 0.f);
        float4 v1 = v0;
        if (n0 + row < N) {
            v0 = src4[(size_t)(n0 + row) * 32 + k8 * 2];
            v1 = src4[(size_t)(n0 + row) * 32 + k8 * 2 + 1];
        }
        short8 sv;
        sv[0] = f2bf(v0.x); sv[1] = f2bf(v0.y); sv[2] = f2bf(v0.z); sv[3] = f2bf(v0.w);
        sv[4] = f2bf(v1.x); sv[5] = f2bf(v1.y); sv[6] = f2bf(v1.z); sv[7] = f2bf(v1.w);
        *reinterpret_cast<short8*>(&nd[row * LDN + k8 * 8]) = sv;
    }
    __syncthreads();   // nd is read-only from here on; no more barriers

    for (int r = 0; r < R; ++r) {
        const short8* wr = Wf + (size_t)r * 2048 + lane;   // [kk][j][lane]

        f32x4 acc[2][8];
#pragma unroll
        for (int t2 = 0; t2 < 2; ++t2)
#pragma unroll
            for (int j = 0; j < 8; ++j) acc[t2][j] = (f32x4)(0.f);

#pragma unroll
        for (int kk = 0; kk < 4; ++kk) {
            short8 a0 = *reinterpret_cast<const short8*>(&nd[(w32 +      m) * LDN + kk * 32 + q8]);
            short8 a1 = *reinterpret_cast<const short8*>(&nd[(w32 + 16 + m) * LDN + kk * 32 + q8]);
#pragma unroll
            for (int j = 0; j < 8; ++j) {
                short8 b = wr[kk * 512 + j * 64];
                acc[0][j] = __builtin_amdgcn_mfma_f32_16x16x32_bf16(a0, b, acc[0][j], 0, 0, 0);
                acc[1][j] = __builtin_amdgcn_mfma_f32_16x16x32_bf16(a1, b, acc[1][j], 0, 0, 0);
            }
        }

#pragma unroll
        for (int t2 = 0; t2 < 2; ++t2) {
            int rowbase = n0 + w32 + t2 * 16 + quad * 4;
#pragma unroll
            for (int reg = 0; reg < 4; ++reg) {
                int n = rowbase + reg;
                if (n < N) {
                    __hip_bfloat16* dst = H + ((size_t)r * N + n) * HTO + m;
#pragma unroll
                    for (int j = 0; j < 8; ++j)
                        dst[j * 16] = __float2bfloat16(acc[t2][j][reg]);
                }
            }
        }
    }
}

// ---------------------------------------------------------------------------
// pull-gather, unrolled x8 (unchanged this round)
// ---------------------------------------------------------------------------
__global__ __launch_bounds__(256)
void gather_kernel(const u64* __restrict__ sorted,
                   const int* __restrict__ cursor,
                   const __hip_bfloat16* __restrict__ H,
                   float* __restrict__ out, int N) {
    const int wave = threadIdx.x >> 6;
    const int lane = threadIdx.x & 63;
    const int n = blockIdx.x * 4 + wave;
    if (n >= N) return;

    int e         = (n == 0) ? 0 : cursor[n - 1];
    const int end = cursor[n];

    float a0 = 0.f, a1 = 0.f, b0 = 0.f, b1 = 0.f;
    float c0 = 0.f, c1 = 0.f, d0 = 0.f, d1 = 0.f;

    const unsigned short* Hu = reinterpret_cast<const unsigned short*>(H);

#define HROW(q) reinterpret_cast<const unsigned int*>( \
        Hu + ((((size_t)((unsigned int)(q) >> 17) & 7) * (size_t)N + \
               ((unsigned int)(q) & 0x1FFFF)) << 7))
#define VAL(q)  __uint_as_float((unsigned int)((q) >> 32))

    for (; e + 8 <= end; e += 8) {
        const u64* p = sorted + __builtin_amdgcn_readfirstlane(e);
        u64 q0 = p[0], q1 = p[1], q2 = p[2], q3 = p[3];
        u64 q4 = p[4], q5 = p[5], q6 = p[6], q7 = p[7];
        unsigned int x0 = HROW(q0)[lane];
        unsigned int x1 = HROW(q1)[lane];
        unsigned int x2 = HROW(q2)[lane];
        unsigned int x3 = HROW(q3)[lane];
        unsigned int x4 = HROW(q4)[lane];
        unsigned int x5 = HROW(q5)[lane];
        unsigned int x6 = HROW(q6)[lane];
        unsigned int x7 = HROW(q7)[lane];
        a0 = fmaf(bflo(x0), VAL(q0), a0); a1 = fmaf(bfhi(x0), VAL(q0), a1);
        b0 = fmaf(bflo(x1), VAL(q1), b0); b1 = fmaf(bfhi(x1), VAL(q1), b1);
        c0 = fmaf(bflo(x2), VAL(q2), c0); c1 = fmaf(bfhi(x2), VAL(q2), c1);
        d0 = fmaf(bflo(x3), VAL(q3), d0); d1 = fmaf(bfhi(x3), VAL(q3), d1);
        a0 = fmaf(bflo(x4), VAL(q4), a0); a1 = fmaf(bfhi(x4), VAL(q4), a1);
        b0 = fmaf(bflo(x5), VAL(q5), b0); b1 = fmaf(bfhi(x5), VAL(q5), b1);
        c0 = fmaf(bflo(x6), VAL(q6), c0); c1 = fmaf(bfhi(x6), VAL(q6), c1);
        d0 = fmaf(bflo(x7), VAL(q7), d0); d1 = fmaf(bfhi(x7), VAL(q7), d1);
    }
    for (; e + 2 <= end; e += 2) {
        const u64* p = sorted + __builtin_amdgcn_readfirstlane(e);
        u64 q0 = p[0], q1 = p[1];
        unsigned int x0 = HROW(q0)[lane];
        unsigned int x1 = HROW(q1)[lane];
        a0 = fmaf(bflo(x0), VAL(q0), a0); a1 = fmaf(bfhi(x0), VAL(q0), a1);
        b0 = fmaf(bflo(x1), VAL(q1), b0); b1 = fmaf(bfhi(x1), VAL(q1), b1);
    }
    if (e < end) {
        u64 q0 = sorted[e];
        unsigned int x0 = HROW(q0)[lane];
        a0 = fmaf(bflo(x0), VAL(q0), a0); a1 = fmaf(bfhi(x0), VAL(q0), a1);
    }
#undef HROW
#undef VAL

    float2 o;
    o.x = fmaxf(a0 + b0 + c0 + d0, 0.f);
    o.y = fmaxf(a1 + b1 + c1 + d1, 0.f);
    *reinterpret_cast<float2*>(out + (size_t)n * HTO + lane * 2) = o;
}

// ---------------------------------------------------------------------------
extern "C" void kernel_launch(void* const* d_in, const int* in_sizes, int n_in,
                              void* d_out, int out_size, void* d_ws, size_t ws_size,
                              hipStream_t stream) {
    const float* nodes   = (const float*)d_in[0];   // [N, HFR] fp32
    const int*   indices = (const int*)d_in[1];     // [2, NNZ] int32
    const float* vals    = (const float*)d_in[2];   // [NNZ] fp32
    const float* weights = (const float*)d_in[3];   // [R, HFR, HTO] fp32

    const int N   = in_sizes[0] / HFR;
    const int nnz = in_sizes[1] / 2;
    const int R   = in_sizes[3] / (HFR * HTO);

    const int* rows = indices;
    const int* cols = indices + nnz;

    // Workspace layout:
    //   H      : [R, N, HTO] bf16   (204.8 MB)
    //   sorted : [nnz] u64          (12.8 MB)
    //   cnt    : [N] int            (0.4 MB)
    //   bsum   : [1024] int         (4 KB)
    //   Wf     : [R*4*8*64] short8  (256 KB)  -- falls back to d_out tail
    char* ws = (char*)d_ws;
    __hip_bfloat16* H = (__hip_bfloat16*)ws;
    size_t off = (size_t)R * N * HTO * sizeof(__hip_bfloat16);
    u64* sorted = (u64*)(ws + off);
    off += (size_t)nnz * sizeof(u64);
    int* cnt = (int*)(ws + off);
    off += (size_t)N * sizeof(int);
    int* bsum = (int*)(ws + off);
    off += 1024 * sizeof(int);

    const size_t WFBYTES = (size_t)R * 4 * 8 * 64 * sizeof(short8);  // 256 KB
    short8* Wf;
    if (off + WFBYTES <= ws_size) {
        Wf = (short8*)(ws + off);
    } else {
        // tail of d_out: written by conv_weights, read by fused_tp, then the
        // gather pass overwrites every element of out afterwards.
        Wf = (short8*)((char*)d_out + (size_t)out_size - WFBYTES);
    }

    float* out = (float*)d_out;

    const int NB = (N + 255) / 256;        // scan blocks (<= 1024)
    const int Tblocks = (N + 127) / 128;   // transform tiles
    const int Pblocks = (nnz + 255) / 256; // place blocks

    // 0) weight pre-swizzle (tiny, 256 KB out)
    conv_weights<<<(R * 4 * 8 * 64) / 256, 256, 0, stream>>>(weights, Wf);
    // 1) zero histogram
    zero_i32<<<NB, 256, 0, stream>>>(cnt, N);
    // 2) degree histogram
    count_kernel<<<Pblocks, 256, 0, stream>>>(rows, cnt, N, nnz);
    // 3) exclusive scan (hierarchical, coalesced)
    scan_reduce<<<NB, 256, 0, stream>>>(cnt, bsum, N);
    scan_block<<<1, 1024, 0, stream>>>(bsum, NB);
    scan_final<<<NB, 256, 0, stream>>>(cnt, bsum, N);
    // 4) transform (MFMA) in parallel with counting-sort placement
    fused_tp<<<Tblocks + Pblocks, 256, 0, stream>>>(nodes, Wf, H,
                                                    rows, cols, vals,
                                                    cnt, sorted, N, R, nnz, Tblocks);
    // 5) pull-gather + relu
    gather_kernel<<<(N + 3) / 4, 256, 0, stream>>>(sorted, cnt, H, out, N);
}